// Round 13
// baseline (184.024 us; speedup 1.0000x reference)
//
#include <hip/hip_runtime.h>

#define NVOX 120000
#define KVOL 27
#define CH 64
#define TOTAL (NVOX * CH)
#define NF4 (TOTAL / 4)
#define EPSV 1e-5f

typedef __attribute__((ext_vector_type(8))) short bf16x8;
typedef __attribute__((ext_vector_type(8))) unsigned short u16x8;
typedef __attribute__((ext_vector_type(4))) float f32x4;
typedef __attribute__((address_space(1))) const void gconst_t;
typedef __attribute__((address_space(3))) void lvoid_t;

__device__ __forceinline__ unsigned short f2bf(float f) {
    unsigned int u = __builtin_bit_cast(unsigned int, f);
    u += 0x7FFFu + ((u >> 16) & 1u);          // RNE
    return (unsigned short)(u >> 16);
}

// ---- prep: weight shuffle only (27 blocks; FB pass deleted) ----------------
// weight fp32 [k][c][d] -> bf16 MFMA-fragment order (validated layout):
//   wtf[((k*8+grp)*64+l)*8+j], grp=(d>>4)*2+(c>>5), l=((c&31)>>3)*16+(d&15),
//   j=c&7.  One k-slice per block: coalesced float4 reads, in-LDS permute,
//   coalesced u16x8 writes. conv now gathers fp32 feats directly (the FB
//   bf16 mirror cost ~8-12 us of prep for a conv kernel that is latency-,
//   not bandwidth-bound).
__global__ void prep(const float* __restrict__ w, unsigned short* __restrict__ wtf,
                     float* __restrict__ stats) {
    __shared__ unsigned short ls[4096];
    const int k = blockIdx.x;
    const int tid = threadIdx.x;
    float4 v[4];
    const float4* src = (const float4*)(w + (size_t)k * 4096 + tid * 16);
#pragma unroll
    for (int i = 0; i < 4; ++i) v[i] = src[i];
#pragma unroll
    for (int e = 0; e < 16; ++e) {                 // e compile-time: no scratch
        const int t = tid * 16 + e;
        const int d = t & 63, c = t >> 6;
        const int grp = (d >> 4) * 2 + (c >> 5);
        const int l = ((c & 31) >> 3) * 16 + (d & 15);
        const int j = c & 7;
        ls[(grp * 64 + l) * 8 + j] = f2bf(((const float*)v)[e]);
    }
    __syncthreads();
    u16x8* dst = (u16x8*)(wtf + (size_t)k * 4096);
    const u16x8* lsv = (const u16x8*)ls;
    dst[tid * 2]     = lsv[tid * 2];
    dst[tid * 2 + 1] = lsv[tid * 2 + 1];
    if (k == 0 && tid < 128) stats[tid] = 0.f;
}

// ---- conv: r2 phase skeleton (58 us, 3x verified) + direct fp32 gather -----
// Identical schedule: 938 blocks x 4 waves x 32 vox, double-buffered 8 KB
// LDS weight stage via global_load_lds, counted end-of-phase s_waitcnt that
// drains EXACTLY the stage while gathers+idx stay in flight across the
// s_barrier. Changes vs r2/r10:
//  - gathers load raw float4 from fp32 feats (4 loads/tile, clamped row,
//    ALWAYS issued) carried across the phase boundary in named ping-pong
//    register sets (r12's proven no-scratch pattern); cvt to bf16 fragments
//    happens at CONSUMPTION (loads then a full phase old -> no mid-phase
//    stall, unlike r0); per-lane cndmask zeroing replaces the FB sentinel.
//  - ballots/masks deleted: MFMAs unconditional (zeroed frags keep padded
//    and invalid rows exactly 0 for BN stats).
// Ledger per phase: stage(2) -> gathers(8) -> idx(2); addr-calc consumption
// of prev idx (youngest of prev 10) drains all prev loads before new issue
// (in-order retirement); at end-of-phase outstanding = 12 -> vmcnt(10)
// drains exactly the stage. k=26: no stage, 10 outstanding, no-op.
// launch_bounds(256,3): ~125 total regs (acc 32 AGPR + ~93 VGPR) vs 170
// budget. No-spill check: WRITE_SIZE must stay ~30.5 MB (r11 lesson).
__launch_bounds__(256, 3)
__global__ void conv_mfma(const float* __restrict__ feats,
                          const unsigned short* __restrict__ WtF,
                          const int* __restrict__ nbr,
                          float* __restrict__ out,
                          float* __restrict__ stats) {
    __shared__ unsigned short wlds[2][4096];   // 2 x 8 KB weight slice buffers
    __shared__ float lstats[128];
    const int tid = threadIdx.x;
    const int lane = tid & 63;
    const int wv = tid >> 6;
    const int m = lane & 15;
    const int q = lane >> 4;
    const int v0 = blockIdx.x * 128 + wv * 32;
    const bool tv[2] = { v0 < NVOX, v0 + 16 < NVOX };
    const int r[2] = { v0 + m, v0 + 16 + m };

    f32x4 acc[2][4];
#pragma unroll
    for (int t = 0; t < 2; ++t)
#pragma unroll
        for (int nt = 0; nt < 4; ++nt)
            acc[t][nt] = (f32x4){0.f, 0.f, 0.f, 0.f};
    if (tid < 128) lstats[tid] = 0.f;

    // ---- prologue: stage slice 0, raw-gather slice 0, idx slice 1 ----
    {
        const unsigned short* g = WtF + wv * 1024 + lane * 8;   // this wave's 2KB
        __builtin_amdgcn_global_load_lds((gconst_t*)g,         (lvoid_t*)&wlds[0][wv * 1024],       16, 0, 0);
        __builtin_amdgcn_global_load_lds((gconst_t*)(g + 512), (lvoid_t*)&wlds[0][wv * 1024 + 512], 16, 0, 0);
    }
    __builtin_amdgcn_sched_barrier(0);

    float4 pA[2][4], pB[2][4];                 // raw pending rows [tile][quarter]
    bool invA[2], invB[2];
    int ixA[2], ixB[2];
#pragma unroll
    for (int t = 0; t < 2; ++t) {
        const int rr = tv[t] ? r[t] : m;       // clamped addr: loads always issue
        const int i0 = nbr[rr];
        const int ii = tv[t] ? i0 : -1;
        invA[t] = (ii < 0);
        const float* row = feats + (size_t)(ii < 0 ? 0 : ii) * CH + q * 8;
        pA[t][0] = *(const float4*)(row);
        pA[t][1] = *(const float4*)(row + 4);
        pA[t][2] = *(const float4*)(row + 32);
        pA[t][3] = *(const float4*)(row + 36);
        const int i1 = nbr[NVOX + rr];
        ixA[t] = tv[t] ? i1 : -1;
    }
    asm volatile("s_waitcnt vmcnt(10) lgkmcnt(0)" ::: "memory");
    __builtin_amdgcn_s_barrier();
    __builtin_amdgcn_sched_barrier(0);

    // one phase: stage k+1, raw-gather k+1 (from ixC), idx k+2, cvt+MFMA k.
    auto phase = [&](const float4 (&pC)[2][4], float4 (&pN)[2][4],
                     const bool (&invC)[2], bool (&invN)[2],
                     const int (&ixC)[2], int (&ixN)[2], const int k) {
        const int nb = k & 1;
        // 1. stage slice k+1 (pinned oldest in this phase's VMEM order)
        if (k + 1 < KVOL) {
            const unsigned short* g = WtF + (size_t)(k + 1) * 4096 + wv * 1024 + lane * 8;
            __builtin_amdgcn_global_load_lds((gconst_t*)g,         (lvoid_t*)&wlds[nb ^ 1][wv * 1024],       16, 0, 0);
            __builtin_amdgcn_global_load_lds((gconst_t*)(g + 512), (lvoid_t*)&wlds[nb ^ 1][wv * 1024 + 512], 16, 0, 0);
        }
        __builtin_amdgcn_sched_barrier(0);

        // 2. raw gathers for slice k+1 (addr consumes ixC -> drains prev loads)
#pragma unroll
        for (int t = 0; t < 2; ++t) {
            const int ii = ixC[t];
            invN[t] = (ii < 0);
            const float* row = feats + (size_t)(ii < 0 ? 0 : ii) * CH + q * 8;
            pN[t][0] = *(const float4*)(row);
            pN[t][1] = *(const float4*)(row + 4);
            pN[t][2] = *(const float4*)(row + 32);
            pN[t][3] = *(const float4*)(row + 36);
        }
        // 3. idx prefetch for slice k+2 (always 2 loads: count-uniform)
        const int kk = (k + 2 < KVOL) ? (k + 2) : 0;
        const int* nbp = nbr + (size_t)kk * NVOX;
#pragma unroll
        for (int t = 0; t < 2; ++t) {
            const int rr = tv[t] ? r[t] : m;
            const int v = nbp[rr];
            ixN[t] = (tv[t] && (k + 2 < KVOL)) ? v : -1;
        }

        // 4. weight fragments for slice k from LDS (conflict-free b128)
        const unsigned short* wk = &wlds[nb][lane * 8];
        bf16x8 bfr[8];
#pragma unroll
        for (int h = 0; h < 8; ++h)
            bfr[h] = *(const bf16x8*)(wk + h * 512);

        // 5. cvt pending raw (a full phase old) -> frags, zero invalid, MFMA
#pragma unroll
        for (int t = 0; t < 2; ++t) {
            bf16x8 a0 = (bf16x8){(short)f2bf(pC[t][0].x), (short)f2bf(pC[t][0].y),
                                 (short)f2bf(pC[t][0].z), (short)f2bf(pC[t][0].w),
                                 (short)f2bf(pC[t][1].x), (short)f2bf(pC[t][1].y),
                                 (short)f2bf(pC[t][1].z), (short)f2bf(pC[t][1].w)};
            bf16x8 a1 = (bf16x8){(short)f2bf(pC[t][2].x), (short)f2bf(pC[t][2].y),
                                 (short)f2bf(pC[t][2].z), (short)f2bf(pC[t][2].w),
                                 (short)f2bf(pC[t][3].x), (short)f2bf(pC[t][3].y),
                                 (short)f2bf(pC[t][3].z), (short)f2bf(pC[t][3].w)};
            if (invC[t]) { a0 = (bf16x8)(short)0; a1 = (bf16x8)(short)0; }
#pragma unroll
            for (int nt = 0; nt < 4; ++nt) {
                acc[t][nt] = __builtin_amdgcn_mfma_f32_16x16x32_bf16(a0, bfr[nt * 2 + 0], acc[t][nt], 0, 0, 0);
                acc[t][nt] = __builtin_amdgcn_mfma_f32_16x16x32_bf16(a1, bfr[nt * 2 + 1], acc[t][nt], 0, 0, 0);
            }
        }

        // 6. drain exactly the stage; gathers+idx stay in flight
        asm volatile("s_waitcnt vmcnt(10)" ::: "memory");
        __builtin_amdgcn_s_barrier();
        __builtin_amdgcn_sched_barrier(0);
    };

    for (int k = 0; k < KVOL - 1; k += 2) {        // pairs (0,1)...(24,25)
        phase(pA, pB, invA, invB, ixA, ixB, k);
        phase(pB, pA, invB, invA, ixB, ixA, k + 1);
    }
    phase(pA, pB, invA, invB, ixA, ixB, KVOL - 1); // k=26: no stage, wait no-op

    // ---- epilogue: stores + block-reduced BN statistics ----
    // D layout: col = m (channel nt*16+m), row = q*4 + rr (voxel within tile)
#pragma unroll
    for (int t = 0; t < 2; ++t) {
        if (tv[t]) {
            float* ob = out + (size_t)(v0 + t * 16 + q * 4) * CH + m;
#pragma unroll
            for (int nt = 0; nt < 4; ++nt)
#pragma unroll
                for (int rr = 0; rr < 4; ++rr)
                    ob[(size_t)rr * CH + nt * 16] = acc[t][nt][rr];
        }
    }

#pragma unroll
    for (int nt = 0; nt < 4; ++nt) {
        float s = 0.f, s2 = 0.f;
#pragma unroll
        for (int t = 0; t < 2; ++t)
#pragma unroll
            for (int rr = 0; rr < 4; ++rr) {
                const float x = acc[t][nt][rr];   // padded/invalid stay exactly 0
                s += x;
                s2 = fmaf(x, x, s2);
            }
        s  += __shfl_xor(s, 16);  s  += __shfl_xor(s, 32);
        s2 += __shfl_xor(s2, 16); s2 += __shfl_xor(s2, 32);
        if (lane < 16) {
            atomicAdd(&lstats[nt * 16 + m], s);
            atomicAdd(&lstats[64 + nt * 16 + m], s2);
        }
    }
    __syncthreads();
    if (tid < 128) atomicAdd(&stats[tid], lstats[tid]);
}

// ---- bn_relu: exact-cover grid (1875*256*4 float4 = NF4), hoisted sb -------
__launch_bounds__(256)
__global__ void bn_relu(float* __restrict__ out, const float* __restrict__ stats,
                        const float* __restrict__ gamma, const float* __restrict__ beta) {
    __shared__ float sb[128];
    const int tid = threadIdx.x;
    if (tid < 64) {
        const float inv_n = 1.0f / (float)NVOX;
        const float mean = stats[tid] * inv_n;
        const float var = stats[64 + tid] * inv_n - mean * mean;
        const float sc = gamma[tid] * rsqrtf(var + EPSV);
        sb[tid] = sc;
        sb[64 + tid] = beta[tid] - mean * sc;
    }
    __syncthreads();
    float4* o4 = (float4*)out;
    const int base = blockIdx.x * 256 + tid;       // 0..479999
    const int cb = (base & 15) * 4;                // 480000 % 16 == 0: constant
    const float s0 = sb[cb + 0], s1 = sb[cb + 1], s2 = sb[cb + 2], s3 = sb[cb + 3];
    const float b0 = sb[64 + cb + 0], b1 = sb[64 + cb + 1], b2 = sb[64 + cb + 2], b3 = sb[64 + cb + 3];
#pragma unroll
    for (int i = 0; i < 4; ++i) {
        const int e = base + i * 480000;
        float4 x = o4[e];
        x.x = fmaxf(fmaf(x.x, s0, b0), 0.f);
        x.y = fmaxf(fmaf(x.y, s1, b1), 0.f);
        x.z = fmaxf(fmaf(x.z, s2, b2), 0.f);
        x.w = fmaxf(fmaf(x.w, s3, b3), 0.f);
        o4[e] = x;
    }
}

extern "C" void kernel_launch(void* const* d_in, const int* in_sizes, int n_in,
                              void* d_out, int out_size, void* d_ws, size_t ws_size,
                              hipStream_t stream) {
    const float* feats  = (const float*)d_in[0];   // [N, 64]
    const float* weight = (const float*)d_in[1];   // [27, 64, 64]
    const float* gamma  = (const float*)d_in[2];   // [64]
    const float* beta   = (const float*)d_in[3];   // [64]
    const int*   nbr    = (const int*)d_in[4];     // [27, N]
    float* out = (float*)d_out;                    // [N, 64]

    // ws layout: [0,512) stats; [512, 512+221184) WtF bf16 frag-order
    float* stats = (float*)d_ws;
    unsigned short* WtF = (unsigned short*)((char*)d_ws + 512);

    prep<<<KVOL, 256, 0, stream>>>(weight, WtF, stats);
    conv_mfma<<<(NVOX + 127) / 128, 256, 0, stream>>>(feats, WtF, nbr, out, stats);
    bn_relu<<<1875, 256, 0, stream>>>(out, stats, gamma, beta);
}